// Round 4
// baseline (37.311 us; speedup 1.0000x reference)
//
#include <hip/hip_runtime.h>
#include <hip/hip_bf16.h>
#include <cstdint>

#define NN 2048
#define FF 64
#define BCC 16

typedef float f32x4 __attribute__((ext_vector_type(4)));
typedef __bf16 bf16x8 __attribute__((ext_vector_type(8)));

// ---------------- workspace layout (bytes) ----------------
// xP   : bf16 packed [16][jt=64][nb=4][lane=64][e=8] = 4,194,304  (off 0)
//        element (bc,jt,nb,(g,l15),e) = x[bc][n = jt*32+8g+e][f = nb*16+l15]
// U    : f32 [16][2048] = 131,072  (off 4,194,304)   e^{f2}
// V    : f32 [16][2048] = 131,072  (off 4,325,376)   e^{0.1 f2}
// CI   : f32 [16][2048] = 131,072  (off 4,456,448)   e^{-0.9 f1}
// ADJB : u8  [bj=256][row=2048] = 524,288 (off 4,587,520)  bj = j/8 bitmask byte
// total ~5.1 MB

// fused prep: blocks [0,512): transpose/pack x + per-row dot/exp tables.
//             blocks [512,4608): adj -> transposed byte bitmask.
__global__ __launch_bounds__(256) void k_prep(const float* __restrict__ x,
        const int* __restrict__ adj,
        const float* __restrict__ a1, const float* __restrict__ a2,
        __hip_bfloat16* __restrict__ xP, float* __restrict__ U,
        float* __restrict__ V, float* __restrict__ CI,
        unsigned char* __restrict__ ADJB) {
    int wid  = threadIdx.x >> 6;
    int lane = threadIdx.x & 63;

    if (blockIdx.x >= 512) {                 // ---- adj packing ----
        int idx = (blockIdx.x - 512) * 4 + wid;   // row*8 + cg
        int row = idx >> 3, cg = idx & 7;
        const int* p = adj + (size_t)row * NN + cg * 256 + lane;
        unsigned long long m0 = __ballot(p[0]   > 0);
        unsigned long long m1 = __ballot(p[64]  > 0);
        unsigned long long m2 = __ballot(p[128] > 0);
        unsigned long long m3 = __ballot(p[192] > 0);
        if (lane < 32) {
            unsigned long long m = (lane < 8) ? m0 : (lane < 16) ? m1
                                 : (lane < 24) ? m2 : m3;
            unsigned char byte = (unsigned char)(m >> (8 * (lane & 7)));
            ADJB[(size_t)(cg * 32 + lane) * NN + row] = byte;
        }
        return;
    }

    // ---- x pack + tables ----
    __shared__ float tile[64][65];
    __shared__ float red[2][64][4];
    int bc = blockIdx.x >> 5;
    int n0 = (blockIdx.x & 31) * 64;
    int tx = lane;
    int ty = wid;
    const float* xp = x + ((size_t)bc * NN + n0) * FF;
    #pragma unroll
    for (int k = 0; k < 16; k++) {
        int nl = ty * 16 + k;
        tile[nl][tx] = xp[(size_t)nl * FF + tx];
    }
    __syncthreads();
    // packed fragment-order write (coalesced 16B per lane)
    int g = lane >> 4, l15 = lane & 15;
    int jt0 = n0 >> 5;
    #pragma unroll
    for (int jl = 0; jl < 2; jl++) {
        bf16x8 val;
        #pragma unroll
        for (int e = 0; e < 8; e++)
            val[e] = (__bf16)tile[jl * 32 + 8 * g + e][ty * 16 + l15];
        ((bf16x8*)xP)[(((size_t)bc * 64 + jt0 + jl) * 4 + ty) * 64 + lane] = val;
    }
    // dots: thread handles row tx, f-quarter ty
    float d1 = 0.f, d2 = 0.f;
    #pragma unroll
    for (int i = 0; i < 16; i++) {
        int f = ty * 16 + i;
        float xv = tile[tx][f];
        d1 += xv * a1[f];
        d2 += xv * a2[f];
    }
    red[0][tx][ty] = d1;
    red[1][tx][ty] = d2;
    __syncthreads();
    if (ty == 0) {
        float f1 = red[0][tx][0] + red[0][tx][1] + red[0][tx][2] + red[0][tx][3];
        float f2 = red[1][tx][0] + red[1][tx][1] + red[1][tx][2] + red[1][tx][3];
        int idx = bc * NN + n0 + tx;
        U[idx]  = expf(f2);
        V[idx]  = expf(0.1f * f2);
        CI[idx] = expf(-0.9f * f1);
    }
}

// main: block = (bc, 32-row i-block); 4 waves, wave jq owns j-quarter (512 j).
// weights w' = adj * max(u_j, Ci*v_j)  (softmax row-scale invariance).
// Two-stage register pipeline: prefetch jt+1 while computing jt.
__global__ __launch_bounds__(256, 4) void k_main(
        const __hip_bfloat16* __restrict__ xP, const float* __restrict__ U,
        const float* __restrict__ V, const float* __restrict__ CI,
        const unsigned char* __restrict__ ADJB, float* __restrict__ out) {
    __shared__ float partial[4][32][66];
    __shared__ float zpart[4][32];

    int jq = threadIdx.x >> 6, lane = threadIdx.x & 63;
    // XCD swizzle: 1024 blocks -> 128 contiguous logical ids per XCD
    int bid  = ((blockIdx.x & 7) << 7) | (blockIdx.x >> 3);
    int bc   = bid >> 6;
    int iblk = bid & 63;
    int i0   = iblk * 32;
    int l15 = lane & 15, g = lane >> 4;

    float Ci[2];
    Ci[0] = CI[bc * NN + i0 + l15];
    Ci[1] = CI[bc * NN + i0 + 16 + l15];

    f32x4 acc[2][4];
    #pragma unroll
    for (int a = 0; a < 2; a++)
        #pragma unroll
        for (int nb = 0; nb < 4; nb++)
            acc[a][nb] = (f32x4){0.f, 0.f, 0.f, 0.f};
    f32x4 accz[2];
    accz[0] = (f32x4){0.f, 0.f, 0.f, 0.f};
    accz[1] = (f32x4){0.f, 0.f, 0.f, 0.f};
    bf16x8 onesf;
    #pragma unroll
    for (int e = 0; e < 8; e++) onesf[e] = (__bf16)1.0f;

    const float* Ubc = U + bc * NN;
    const float* Vbc = V + bc * NN;
    const bf16x8* xPbc = (const bf16x8*)xP + (size_t)bc * 16384;

    // pipeline stage registers (named, static indexing only)
    bf16x8 a_bf0, a_bf1, a_bf2, a_bf3, b_bf0, b_bf1, b_bf2, b_bf3;
    f32x4  a_u0, a_u1, a_v0, a_v1, b_u0, b_u1, b_v0, b_v1;
    uint32_t a_m0, a_m1, b_m0, b_m1;

#define LOADM(p, jtv) do {                                                    \
        int jt_ = (jtv);                                                      \
        const bf16x8* xpw_ = xPbc + ((size_t)jt_ << 8) + lane;                \
        p##bf0 = xpw_[0]; p##bf1 = xpw_[64];                                  \
        p##bf2 = xpw_[128]; p##bf3 = xpw_[192];                               \
        const f32x4* up_ = (const f32x4*)Ubc + jt_ * 8 + 2 * g;               \
        const f32x4* vp_ = (const f32x4*)Vbc + jt_ * 8 + 2 * g;               \
        p##u0 = up_[0]; p##u1 = up_[1]; p##v0 = vp_[0]; p##v1 = vp_[1];       \
        const unsigned char* ap_ = ADJB + ((size_t)(jt_ * 4 + g) << 11) + i0 + l15; \
        p##m0 = ap_[0]; p##m1 = ap_[16];                                      \
    } while (0)

#define COMP(p) do {                                                          \
        _Pragma("unroll")                                                     \
        for (int a = 0; a < 2; a++) {                                         \
            uint32_t m8_ = a ? p##m1 : p##m0;                                 \
            float Ca_ = Ci[a];                                                \
            bf16x8 af_;                                                       \
            _Pragma("unroll")                                                 \
            for (int t = 0; t < 8; t++) {                                     \
                float uu_ = (t < 4) ? p##u0[t] : p##u1[t - 4];                \
                float vv_ = (t < 4) ? p##v0[t] : p##v1[t - 4];                \
                float m_  = fmaxf(uu_, Ca_ * vv_);                            \
                af_[t] = ((m8_ >> t) & 1u) ? (__bf16)m_ : (__bf16)0.f;        \
            }                                                                 \
            acc[a][0] = __builtin_amdgcn_mfma_f32_16x16x32_bf16(af_, p##bf0, acc[a][0], 0, 0, 0); \
            acc[a][1] = __builtin_amdgcn_mfma_f32_16x16x32_bf16(af_, p##bf1, acc[a][1], 0, 0, 0); \
            acc[a][2] = __builtin_amdgcn_mfma_f32_16x16x32_bf16(af_, p##bf2, acc[a][2], 0, 0, 0); \
            acc[a][3] = __builtin_amdgcn_mfma_f32_16x16x32_bf16(af_, p##bf3, acc[a][3], 0, 0, 0); \
            accz[a]   = __builtin_amdgcn_mfma_f32_16x16x32_bf16(af_, onesf,  accz[a],   0, 0, 0); \
        }                                                                     \
    } while (0)

    int jt0 = jq * 16;
    LOADM(a_, jt0);
    for (int it = 0; it < 7; it++) {
        LOADM(b_, jt0 + 2 * it + 1);
        COMP(a_);
        LOADM(a_, jt0 + 2 * it + 2);
        COMP(b_);
    }
    LOADM(b_, jt0 + 15);
    COMP(a_);
    COMP(b_);
#undef LOADM
#undef COMP

    // dump all partials (acc + z) to LDS
    #pragma unroll
    for (int a = 0; a < 2; a++)
        #pragma unroll
        for (int nb = 0; nb < 4; nb++)
            #pragma unroll
            for (int r = 0; r < 4; r++)
                partial[jq][16 * a + 4 * g + r][nb * 16 + l15] = acc[a][nb][r];
    if (l15 == 0) {
        #pragma unroll
        for (int a = 0; a < 2; a++)
            #pragma unroll
            for (int r = 0; r < 4; r++)
                zpart[jq][16 * a + 4 * g + r] = accz[a][r];
    }
    __syncthreads();

    // wave jq reduces rows [8jq, 8jq+8) and stores
    float* outp = out + ((size_t)bc * NN + i0) * FF;
    #pragma unroll
    for (int rr = 0; rr < 8; rr++) {
        int il = jq * 8 + rr;
        float zi = zpart[0][il] + zpart[1][il] + zpart[2][il] + zpart[3][il];
        float s  = partial[0][il][lane] + partial[1][il][lane]
                 + partial[2][il][lane] + partial[3][il][lane];
        outp[(size_t)il * FF + lane] = s / zi;
    }
}

extern "C" void kernel_launch(void* const* d_in, const int* in_sizes, int n_in,
                              void* d_out, int out_size, void* d_ws, size_t ws_size,
                              hipStream_t stream) {
    const float* x  = (const float*)d_in[0];
    const int* adj  = (const int*)d_in[1];
    const float* a1 = (const float*)d_in[2];
    const float* a2 = (const float*)d_in[3];
    float* out = (float*)d_out;

    char* ws = (char*)d_ws;
    __hip_bfloat16* xP = (__hip_bfloat16*)ws;
    float* U  = (float*)(ws + 4194304);
    float* V  = (float*)(ws + 4325376);
    float* CI = (float*)(ws + 4456448);
    unsigned char* ADJB = (unsigned char*)(ws + 4587520);

    k_prep<<<512 + 4096, 256, 0, stream>>>(x, adj, a1, a2, xP, U, V, CI, ADJB);
    k_main<<<BCC * 64, 256, 0, stream>>>(xP, U, V, CI, ADJB, out);
}

// Round 5
// 33.595 us; speedup vs baseline: 1.1106x; 1.1106x over previous
//
#include <hip/hip_runtime.h>
#include <hip/hip_bf16.h>
#include <cstdint>

#define NN 2048
#define FF 64
#define BCC 16

typedef float f32x4 __attribute__((ext_vector_type(4)));
typedef __bf16 bf16x8 __attribute__((ext_vector_type(8)));
typedef uint32_t u32x4 __attribute__((ext_vector_type(4)));

// ---------------- workspace layout (bytes) ----------------
// xP   : bf16 packed [16][jt=64][nb=4][lane=64][e=8] = 4,194,304  (off 0)
//        element (bc,jt,nb,(g,l15),e) = x[bc][n = jt*32+8g+e][f = nb*16+l15]
// U    : f32 [16][2048] = 131,072  (off 4,194,304)   e^{f2}
// V    : f32 [16][2048] = 131,072  (off 4,325,376)   e^{0.1 f2}
// CI   : f32 [16][2048] = 131,072  (off 4,456,448)   e^{-0.9 f1}
// ADJP : u8  [row=2048][g=4][jt=64] = 524,288 (off 4,587,520)
//        byte (row,g,jt) bits t = adj[row][jt*32+8g+t]
// total ~5.1 MB

// fused prep: blocks [0,512): transpose/pack x + per-row dot/exp tables.
//             blocks [512,4608): adj -> ADJP byte table.
__global__ __launch_bounds__(256) void k_prep(const float* __restrict__ x,
        const int* __restrict__ adj,
        const float* __restrict__ a1, const float* __restrict__ a2,
        __hip_bfloat16* __restrict__ xP, float* __restrict__ U,
        float* __restrict__ V, float* __restrict__ CI,
        unsigned char* __restrict__ ADJP) {
    int wid  = threadIdx.x >> 6;
    int lane = threadIdx.x & 63;

    if (blockIdx.x >= 512) {                 // ---- adj packing ----
        int idx = (blockIdx.x - 512) * 4 + wid;   // row*8 + cg
        int row = idx >> 3, cg = idx & 7;
        const int* p = adj + (size_t)row * NN + cg * 256 + lane;
        unsigned long long m0 = __ballot(p[0]   > 0);
        unsigned long long m1 = __ballot(p[64]  > 0);
        unsigned long long m2 = __ballot(p[128] > 0);
        unsigned long long m3 = __ballot(p[192] > 0);
        if (lane < 32) {
            int q = lane >> 3, s = lane & 7;          // chunk c = cg*4+q
            unsigned long long m = (q == 0) ? m0 : (q == 1) ? m1
                                 : (q == 2) ? m2 : m3;
            unsigned char byte = (unsigned char)(m >> (8 * s));
            int jt = (cg * 4 + q) * 2 + (s >> 2);
            int g  = s & 3;
            ADJP[(size_t)row * 256 + g * 64 + jt] = byte;
        }
        return;
    }

    // ---- x pack + tables ----
    __shared__ float tile[64][65];
    __shared__ float red[2][64][4];
    int bc = blockIdx.x >> 5;
    int n0 = (blockIdx.x & 31) * 64;
    int tx = lane;
    int ty = wid;
    const float* xp = x + ((size_t)bc * NN + n0) * FF;
    #pragma unroll
    for (int k = 0; k < 16; k++) {
        int nl = ty * 16 + k;
        tile[nl][tx] = xp[(size_t)nl * FF + tx];
    }
    __syncthreads();
    // packed fragment-order write (coalesced 16B per lane)
    int g = lane >> 4, l15 = lane & 15;
    int jt0 = n0 >> 5;
    #pragma unroll
    for (int jl = 0; jl < 2; jl++) {
        bf16x8 val;
        #pragma unroll
        for (int e = 0; e < 8; e++)
            val[e] = (__bf16)tile[jl * 32 + 8 * g + e][ty * 16 + l15];
        ((bf16x8*)xP)[(((size_t)bc * 64 + jt0 + jl) * 4 + ty) * 64 + lane] = val;
    }
    // dots: thread handles row tx, f-quarter ty
    float d1 = 0.f, d2 = 0.f;
    #pragma unroll
    for (int i = 0; i < 16; i++) {
        int f = ty * 16 + i;
        float xv = tile[tx][f];
        d1 += xv * a1[f];
        d2 += xv * a2[f];
    }
    red[0][tx][ty] = d1;
    red[1][tx][ty] = d2;
    __syncthreads();
    if (ty == 0) {
        float f1 = red[0][tx][0] + red[0][tx][1] + red[0][tx][2] + red[0][tx][3];
        float f2 = red[1][tx][0] + red[1][tx][1] + red[1][tx][2] + red[1][tx][3];
        int idx = bc * NN + n0 + tx;
        U[idx]  = expf(f2);
        V[idx]  = expf(0.1f * f2);
        CI[idx] = expf(-0.9f * f1);
    }
}

union SmemT {
    struct { float u[2048]; float v[2048]; uint32_t lut[256][4]; } a;  // 20.5 KB
    struct { float part[4][32][66]; float z[4][32]; } b;               // 34.3 KB
};

// main: block = (bc, 32-row i-block); 4 waves, wave jq owns j-quarter (512 j).
// weights w' = adj * max(u_j, Ci*v_j)  (softmax row-scale invariance).
// U/V staged in LDS; adjacency in registers; mask applied via LDS LUT AND.
__global__ __launch_bounds__(256, 4) void k_main(
        const __hip_bfloat16* __restrict__ xP, const float* __restrict__ U,
        const float* __restrict__ V, const float* __restrict__ CI,
        const unsigned char* __restrict__ ADJP, float* __restrict__ out) {
    __shared__ SmemT sm;

    int tid = threadIdx.x;
    int jq = tid >> 6, lane = tid & 63;
    // XCD swizzle: 1024 blocks -> 128 contiguous logical ids per XCD
    int bid  = ((blockIdx.x & 7) << 7) | (blockIdx.x >> 3);
    int bc   = bid >> 6;
    int iblk = bid & 63;
    int i0   = iblk * 32;
    int l15 = lane & 15, g = lane >> 4;

    // ---- prologue: adjacency regs (one-time scattered loads, overlapped) ----
    u32x4 adjw0 = *(const u32x4*)(ADJP + (size_t)(i0 + l15) * 256 + g * 64 + jq * 16);
    u32x4 adjw1 = *(const u32x4*)(ADJP + (size_t)(i0 + 16 + l15) * 256 + g * 64 + jq * 16);
    float Ci0 = CI[bc * NN + i0 + l15];
    float Ci1 = CI[bc * NN + i0 + 16 + l15];

    // ---- stage U/V into LDS (coalesced, 2 f32x4 per thread per table) ----
    const f32x4* Ug = (const f32x4*)(U + bc * NN);
    const f32x4* Vg = (const f32x4*)(V + bc * NN);
    ((f32x4*)sm.a.u)[tid]       = Ug[tid];
    ((f32x4*)sm.a.u)[tid + 256] = Ug[tid + 256];
    ((f32x4*)sm.a.v)[tid]       = Vg[tid];
    ((f32x4*)sm.a.v)[tid + 256] = Vg[tid + 256];
    // ---- build mask LUT: entry b -> 4 u32 AND-masks for bf16 pairs ----
    {
        uint32_t bb = tid;  // 256 threads = 256 entries
        u32x4 lv;
        #pragma unroll
        for (int w = 0; w < 4; w++)
            lv[w] = (((bb >> (2 * w)) & 1u) ? 0xFFFFu : 0u)
                  | (((bb >> (2 * w + 1)) & 1u) ? 0xFFFF0000u : 0u);
        *(u32x4*)sm.a.lut[bb] = lv;
    }
    __syncthreads();

    f32x4 acc[2][4];
    #pragma unroll
    for (int a = 0; a < 2; a++)
        #pragma unroll
        for (int nb = 0; nb < 4; nb++)
            acc[a][nb] = (f32x4){0.f, 0.f, 0.f, 0.f};
    f32x4 accz0 = (f32x4){0.f, 0.f, 0.f, 0.f};
    f32x4 accz1 = (f32x4){0.f, 0.f, 0.f, 0.f};
    bf16x8 onesf;
    #pragma unroll
    for (int e = 0; e < 8; e++) onesf[e] = (__bf16)1.0f;

    const bf16x8* xPbc = (const bf16x8*)xP + (size_t)bc * 16384;

    bf16x8 A_0, A_1, A_2, A_3, B_0, B_1, B_2, B_3;

#define LOADX(P, J) do {                                                      \
        const bf16x8* xw_ = xPbc + (((size_t)(jq * 16 + (J))) << 8) + lane;   \
        P##0 = xw_[0]; P##1 = xw_[64]; P##2 = xw_[128]; P##3 = xw_[192];      \
    } while (0)

#define COMP(P, J) do {                                                       \
        const int jo_ = (jq * 16 + (J)) * 32 + 8 * g;                         \
        f32x4 cu0 = *(const f32x4*)&sm.a.u[jo_];                              \
        f32x4 cu1 = *(const f32x4*)&sm.a.u[jo_ + 4];                          \
        f32x4 cv0 = *(const f32x4*)&sm.a.v[jo_];                              \
        f32x4 cv1 = *(const f32x4*)&sm.a.v[jo_ + 4];                          \
        uint32_t mb0 = (adjw0[(J) >> 2] >> (((J) & 3) * 8)) & 0xffu;          \
        uint32_t mb1 = (adjw1[(J) >> 2] >> (((J) & 3) * 8)) & 0xffu;          \
        u32x4 msk0 = *(const u32x4*)sm.a.lut[mb0];                            \
        u32x4 msk1 = *(const u32x4*)sm.a.lut[mb1];                            \
        bf16x8 af0, af1;                                                      \
        _Pragma("unroll")                                                     \
        for (int t = 0; t < 8; t++) {                                         \
            float uu = (t < 4) ? cu0[t] : cu1[t - 4];                         \
            float vv = (t < 4) ? cv0[t] : cv1[t - 4];                         \
            af0[t] = (__bf16)fmaxf(uu, Ci0 * vv);                             \
            af1[t] = (__bf16)fmaxf(uu, Ci1 * vv);                             \
        }                                                                     \
        af0 = __builtin_bit_cast(bf16x8, __builtin_bit_cast(u32x4, af0) & msk0); \
        af1 = __builtin_bit_cast(bf16x8, __builtin_bit_cast(u32x4, af1) & msk1); \
        acc[0][0] = __builtin_amdgcn_mfma_f32_16x16x32_bf16(af0, P##0, acc[0][0], 0, 0, 0); \
        acc[0][1] = __builtin_amdgcn_mfma_f32_16x16x32_bf16(af0, P##1, acc[0][1], 0, 0, 0); \
        acc[0][2] = __builtin_amdgcn_mfma_f32_16x16x32_bf16(af0, P##2, acc[0][2], 0, 0, 0); \
        acc[0][3] = __builtin_amdgcn_mfma_f32_16x16x32_bf16(af0, P##3, acc[0][3], 0, 0, 0); \
        accz0     = __builtin_amdgcn_mfma_f32_16x16x32_bf16(af0, onesf, accz0, 0, 0, 0);    \
        acc[1][0] = __builtin_amdgcn_mfma_f32_16x16x32_bf16(af1, P##0, acc[1][0], 0, 0, 0); \
        acc[1][1] = __builtin_amdgcn_mfma_f32_16x16x32_bf16(af1, P##1, acc[1][1], 0, 0, 0); \
        acc[1][2] = __builtin_amdgcn_mfma_f32_16x16x32_bf16(af1, P##2, acc[1][2], 0, 0, 0); \
        acc[1][3] = __builtin_amdgcn_mfma_f32_16x16x32_bf16(af1, P##3, acc[1][3], 0, 0, 0); \
        accz1     = __builtin_amdgcn_mfma_f32_16x16x32_bf16(af1, onesf, accz1, 0, 0, 0);    \
    } while (0)

    LOADX(A_, 0); LOADX(B_, 1);
    COMP(A_, 0);  LOADX(A_, 2);
    COMP(B_, 1);  LOADX(B_, 3);
    COMP(A_, 2);  LOADX(A_, 4);
    COMP(B_, 3);  LOADX(B_, 5);
    COMP(A_, 4);  LOADX(A_, 6);
    COMP(B_, 5);  LOADX(B_, 7);
    COMP(A_, 6);  LOADX(A_, 8);
    COMP(B_, 7);  LOADX(B_, 9);
    COMP(A_, 8);  LOADX(A_, 10);
    COMP(B_, 9);  LOADX(B_, 11);
    COMP(A_, 10); LOADX(A_, 12);
    COMP(B_, 11); LOADX(B_, 13);
    COMP(A_, 12); LOADX(A_, 14);
    COMP(B_, 13); LOADX(B_, 15);
    COMP(A_, 14);
    COMP(B_, 15);
#undef LOADX
#undef COMP

    __syncthreads();   // staging region dead; safe to overwrite with epilogue

    #pragma unroll
    for (int a = 0; a < 2; a++)
        #pragma unroll
        for (int nb = 0; nb < 4; nb++)
            #pragma unroll
            for (int r = 0; r < 4; r++)
                sm.b.part[jq][16 * a + 4 * g + r][nb * 16 + l15] = acc[a][nb][r];
    if (l15 == 0) {
        #pragma unroll
        for (int r = 0; r < 4; r++) {
            sm.b.z[jq][4 * g + r]      = accz0[r];
            sm.b.z[jq][16 + 4 * g + r] = accz1[r];
        }
    }
    __syncthreads();

    // wave jq reduces rows [8jq, 8jq+8) and stores
    float* outp = out + ((size_t)bc * NN + i0) * FF;
    #pragma unroll
    for (int rr = 0; rr < 8; rr++) {
        int il = jq * 8 + rr;
        float zi = sm.b.z[0][il] + sm.b.z[1][il] + sm.b.z[2][il] + sm.b.z[3][il];
        float s  = sm.b.part[0][il][lane] + sm.b.part[1][il][lane]
                 + sm.b.part[2][il][lane] + sm.b.part[3][il][lane];
        outp[(size_t)il * FF + lane] = s / zi;
    }
}

extern "C" void kernel_launch(void* const* d_in, const int* in_sizes, int n_in,
                              void* d_out, int out_size, void* d_ws, size_t ws_size,
                              hipStream_t stream) {
    const float* x  = (const float*)d_in[0];
    const int* adj  = (const int*)d_in[1];
    const float* a1 = (const float*)d_in[2];
    const float* a2 = (const float*)d_in[3];
    float* out = (float*)d_out;

    char* ws = (char*)d_ws;
    __hip_bfloat16* xP = (__hip_bfloat16*)ws;
    float* U  = (float*)(ws + 4194304);
    float* V  = (float*)(ws + 4325376);
    float* CI = (float*)(ws + 4456448);
    unsigned char* ADJP = (unsigned char*)(ws + 4587520);

    k_prep<<<512 + 4096, 256, 0, stream>>>(x, adj, a1, a2, xP, U, V, CI, ADJP);
    k_main<<<BCC * 64, 256, 0, stream>>>(xP, U, V, CI, ADJP, out);
}